// Round 1
// baseline (127.875 us; speedup 1.0000x reference)
//
#include <hip/hip_runtime.h>

// HyperLinear: y[b,o] = sum_i x[b,i]*(target_w[o,i] + w[b,o,i]) + target_b[o] + bias[b,o]
// Restructured:
//   c[i,m]      = fcwp_b[i*64+m] + sum_l index[l]*fcwi_w[i*64+m,l] + fcwi_b[i*64+m]
//   w[b,i,m]    = sum_p h[b,p]*fcwp_w[i*64+m,p] + c[i,m]
//   t[b,m]      = sum_i x[b,i]*w[b,i,m]
//   y[b,o]      = sum_i x[b,i]*target_w[o,i] + sum_m t[b,m]*fcwe_w[o,m]
//               + fcwe_b[o]*sum_i x[b,i] + sum_p h[b,p]*fcbp_w[o,p] + bias_const[o]

#define B_TOT 2048
#define NP    8
#define NL    4
#define CIN   256
#define COUT  256
#define MID   64
#define SPB   4   // samples per block

__global__ __launch_bounds__(256) void precompute_kernel(
    const float* __restrict__ index,
    const float* __restrict__ target_b,
    const float* __restrict__ fcwp_b,
    const float* __restrict__ fcwi_w,
    const float* __restrict__ fcwi_b,
    const float* __restrict__ fcbp_b,
    const float* __restrict__ fcbi_w,
    const float* __restrict__ fcbi_b,
    float* __restrict__ c,           // [CIN*MID]
    float* __restrict__ bias_const)  // [COUT]
{
    int gid = blockIdx.x * blockDim.x + threadIdx.x;
    float i0 = index[0], i1 = index[1], i2 = index[2], i3 = index[3];
    if (gid < CIN * MID) {
        const float* wi = fcwi_w + (size_t)gid * NL;
        c[gid] = fcwp_b[gid] + fcwi_b[gid]
               + i0 * wi[0] + i1 * wi[1] + i2 * wi[2] + i3 * wi[3];
    } else if (gid < CIN * MID + COUT) {
        int o = gid - CIN * MID;
        const float* bi = fcbi_w + (size_t)o * NL;
        bias_const[o] = target_b[o] + fcbp_b[o] + fcbi_b[o]
                      + i0 * bi[0] + i1 * bi[1] + i2 * bi[2] + i3 * bi[3];
    }
}

__global__ __launch_bounds__(256) void hyper_main_kernel(
    const float* __restrict__ x,         // [B, CIN]
    const float* __restrict__ h,         // [B, NP]
    const float* __restrict__ target_w,  // [COUT, CIN]
    const float* __restrict__ fcwp_w,    // [CIN*MID, NP]
    const float* __restrict__ fcwe_w,    // [COUT, MID]
    const float* __restrict__ fcwe_b,    // [COUT]
    const float* __restrict__ fcbp_w,    // [COUT, NP]
    const float* __restrict__ c,         // [CIN*MID]
    const float* __restrict__ bias_const,// [COUT]
    float* __restrict__ out)             // [B, COUT]
{
    __shared__ float xl[SPB][CIN];    // 4 KB
    __shared__ float hl[SPB][NP];
    __shared__ float red[256][SPB];   // 4 KB
    __shared__ float tl[SPB][MID];    // 1 KB
    __shared__ float sxl[SPB];

    const int tid = threadIdx.x;
    const int b0  = blockIdx.x * SPB;

    // stage x, h to LDS (coalesced)
    #pragma unroll
    for (int s = 0; s < SPB; ++s)
        xl[s][tid] = x[(size_t)(b0 + s) * CIN + tid];
    if (tid < SPB * NP)
        hl[tid >> 3][tid & 7] = h[(size_t)b0 * NP + tid];
    __syncthreads();

    // sum of x per sample (for fcwe_b term)
    if (tid < SPB) {
        float ssum = 0.f;
        for (int i = 0; i < CIN; ++i) ssum += xl[tid][i];
        sxl[tid] = ssum;
    }

    // h into registers (all threads hold all SPB samples' h)
    float hr[SPB][NP];
    #pragma unroll
    for (int s = 0; s < SPB; ++s)
        #pragma unroll
        for (int p = 0; p < NP; ++p)
            hr[s][p] = hl[s][p];

    // --- step 2: t[s][m] = sum_i x[s][i] * (c[i,m] + h[s]·fcwp_w[i*64+m,:]) ---
    // wave-lane = m (0..63), wave index g = i-group (64 i's each)
    const int m = tid & 63;
    const int g = tid >> 6;

    float acc[SPB] = {0.f, 0.f, 0.f, 0.f};
    #pragma unroll 4
    for (int ii = 0; ii < 64; ++ii) {
        int i = g * 64 + ii;
        const float* wrow = fcwp_w + (size_t)(i * MID + m) * NP;
        float4 w0 = *(const float4*)(wrow);
        float4 w1 = *(const float4*)(wrow + 4);
        float cim = c[i * MID + m];
        #pragma unroll
        for (int s = 0; s < SPB; ++s) {
            float e = cim
                + w0.x * hr[s][0] + w0.y * hr[s][1] + w0.z * hr[s][2] + w0.w * hr[s][3]
                + w1.x * hr[s][4] + w1.y * hr[s][5] + w1.z * hr[s][6] + w1.w * hr[s][7];
            acc[s] += xl[s][i] * e;
        }
    }
    #pragma unroll
    for (int s = 0; s < SPB; ++s) red[tid][s] = acc[s];
    __syncthreads();
    if (tid < MID) {
        #pragma unroll
        for (int s = 0; s < SPB; ++s)
            tl[s][tid] = red[tid][s] + red[64 + tid][s]
                       + red[128 + tid][s] + red[192 + tid][s];
    }
    __syncthreads();

    // --- step 4: per-output epilogue, o = tid ---
    const int o = tid;
    float y[SPB];
    const float bc  = bias_const[o];
    const float web = fcwe_b[o];
    #pragma unroll
    for (int s = 0; s < SPB; ++s) y[s] = bc + web * sxl[s];

    const float* twrow = target_w + (size_t)o * CIN;
    for (int i = 0; i < CIN; i += 8) {
        float4 t0 = *(const float4*)(twrow + i);
        float4 t1 = *(const float4*)(twrow + i + 4);
        #pragma unroll
        for (int s = 0; s < SPB; ++s) {
            y[s] += t0.x * xl[s][i]     + t0.y * xl[s][i + 1]
                  + t0.z * xl[s][i + 2] + t0.w * xl[s][i + 3]
                  + t1.x * xl[s][i + 4] + t1.y * xl[s][i + 5]
                  + t1.z * xl[s][i + 6] + t1.w * xl[s][i + 7];
        }
    }
    const float* werow = fcwe_w + (size_t)o * MID;
    for (int mm = 0; mm < MID; mm += 4) {
        float4 we = *(const float4*)(werow + mm);
        #pragma unroll
        for (int s = 0; s < SPB; ++s) {
            y[s] += we.x * tl[s][mm]     + we.y * tl[s][mm + 1]
                  + we.z * tl[s][mm + 2] + we.w * tl[s][mm + 3];
        }
    }
    const float* bprow = fcbp_w + (size_t)o * NP;
    float4 bp0 = *(const float4*)(bprow);
    float4 bp1 = *(const float4*)(bprow + 4);
    #pragma unroll
    for (int s = 0; s < SPB; ++s) {
        y[s] += bp0.x * hr[s][0] + bp0.y * hr[s][1] + bp0.z * hr[s][2] + bp0.w * hr[s][3]
              + bp1.x * hr[s][4] + bp1.y * hr[s][5] + bp1.z * hr[s][6] + bp1.w * hr[s][7];
    }
    #pragma unroll
    for (int s = 0; s < SPB; ++s)
        out[(size_t)(b0 + s) * COUT + o] = y[s];
}

extern "C" void kernel_launch(void* const* d_in, const int* in_sizes, int n_in,
                              void* d_out, int out_size, void* d_ws, size_t ws_size,
                              hipStream_t stream) {
    const float* x        = (const float*)d_in[0];
    const float* h        = (const float*)d_in[1];
    const float* index    = (const float*)d_in[2];
    const float* target_w = (const float*)d_in[3];
    const float* target_b = (const float*)d_in[4];
    const float* fcwp_w   = (const float*)d_in[5];
    const float* fcwp_b   = (const float*)d_in[6];
    const float* fcwi_w   = (const float*)d_in[7];
    const float* fcwi_b   = (const float*)d_in[8];
    const float* fcwe_w   = (const float*)d_in[9];
    const float* fcwe_b   = (const float*)d_in[10];
    const float* fcbp_w   = (const float*)d_in[11];
    const float* fcbp_b   = (const float*)d_in[12];
    const float* fcbi_w   = (const float*)d_in[13];
    const float* fcbi_b   = (const float*)d_in[14];
    float* out = (float*)d_out;

    float* c          = (float*)d_ws;          // 16384 floats
    float* bias_const = c + CIN * MID;         // 256 floats

    precompute_kernel<<<(CIN * MID + COUT + 255) / 256, 256, 0, stream>>>(
        index, target_b, fcwp_b, fcwi_w, fcwi_b, fcbp_b, fcbi_w, fcbi_b,
        c, bias_const);

    hyper_main_kernel<<<B_TOT / SPB, 256, 0, stream>>>(
        x, h, target_w, fcwp_w, fcwe_w, fcwe_b, fcbp_w, c, bias_const, out);
}

// Round 2
// 96.113 us; speedup vs baseline: 1.3305x; 1.3305x over previous
//
#include <hip/hip_runtime.h>

// HyperLinear via one bf16 MFMA GEMM + fp32 epilogue.
//
//  Y_all = x @ B_big^T   (M=2048, K=256, N=896 bf16 MFMA, fp32 accum)
//    B_big rows [0,512):   Wp[n=m*8+p][i] = fcwp_w[(i*64+m)*8+p]
//    B_big rows [512,576): c[m][i] = fcwp_b[i*64+m] + fcwi_b[..] + index·fcwi_w[..]
//    B_big rows [576,832): target_w[o][i]
//    B_big row  832:       ones  (gives sx[b] = sum_i x[b,i])
//    B_big rows [833,896): zeros (tile padding)
//  Epilogue (fp32):
//    t[b,m] = sum_p h[b,p]*Y[b, m*8+p] + Y[b, 512+m]
//    y[b,o] = Y[b,576+o] + sum_m t[b,m]*fcwe_w[o,m] + fcwe_b[o]*Y[b,832]
//           + sum_p h[b,p]*fcbp_w[o,p] + bias_const[o]
//    bias_const[o] = target_b[o] + fcbp_b[o] + fcbi_b[o] + index·fcbi_w[o,:]

#define B_TOT 2048
#define NP    8
#define NL    4
#define CIN   256
#define COUT  256
#define MID   64
#define NBIG  896          // 832 used + 64 pad (14 tiles of 64)
#define LDSK  136          // 128 + 8 pad (row = 272 B, 16B aligned, 2-way-free banks)

typedef short  short8  __attribute__((ext_vector_type(8)));
typedef float  floatx4 __attribute__((ext_vector_type(4)));

__device__ __forceinline__ unsigned short f2bf(float f) {
    union { float f; unsigned u; } v; v.f = f;
    unsigned r = v.u + 0x7FFFu + ((v.u >> 16) & 1u);
    return (unsigned short)(r >> 16);
}

// ---------------- setup: build xbf, B_big (bf16), bias_const ----------------
__global__ __launch_bounds__(256) void setup_kernel(
    const float* __restrict__ x, const float* __restrict__ index,
    const float* __restrict__ target_w, const float* __restrict__ target_b,
    const float* __restrict__ fcwp_w, const float* __restrict__ fcwp_b,
    const float* __restrict__ fcwi_w, const float* __restrict__ fcwi_b,
    const float* __restrict__ fcbp_b,
    const float* __restrict__ fcbi_w, const float* __restrict__ fcbi_b,
    unsigned short* __restrict__ xbf, unsigned short* __restrict__ Bb,
    float* __restrict__ bias_const)
{
    int gid = blockIdx.x * 256 + threadIdx.x;
    if (gid < 131072) {                       // x -> bf16, 4 elems/thread
        float4 v = *(const float4*)(x + (size_t)gid * 4);
        ushort4 o;
        o.x = f2bf(v.x); o.y = f2bf(v.y); o.z = f2bf(v.z); o.w = f2bf(v.w);
        *(ushort4*)(xbf + (size_t)gid * 4) = o;
    } else if (gid < 262144) {                // permuted fcwp_w rows [0,512)
        int e = gid - 131072;                 // e = i*512 + m*8 + p
        int n = e & 511, i = e >> 9;
        Bb[n * CIN + i] = f2bf(fcwp_w[e]);
    } else if (gid < 278528) {                // c rows [512,576)
        int e = gid - 262144;                 // e = i*64 + m
        int i = e >> 6, m = e & 63;
        float v = fcwp_b[e] + fcwi_b[e]
                + index[0] * fcwi_w[e * 4]     + index[1] * fcwi_w[e * 4 + 1]
                + index[2] * fcwi_w[e * 4 + 2] + index[3] * fcwi_w[e * 4 + 3];
        Bb[(512 + m) * CIN + i] = f2bf(v);
    } else if (gid < 344064) {                // target_w rows [576,832)
        int e = gid - 278528;
        Bb[576 * CIN + e] = f2bf(target_w[e]);
    } else if (gid < 344320) {                // ones row 832
        Bb[832 * CIN + (gid - 344064)] = f2bf(1.0f);
    } else if (gid < 360448) {                // zero rows [833,896)
        Bb[833 * CIN + (gid - 344320)] = 0;
    } else if (gid < 360704) {                // bias_const
        int o = gid - 360448;
        bias_const[o] = target_b[o] + fcbp_b[o] + fcbi_b[o]
                      + index[0] * fcbi_w[o * 4]     + index[1] * fcbi_w[o * 4 + 1]
                      + index[2] * fcbi_w[o * 4 + 2] + index[3] * fcbi_w[o * 4 + 3];
    }
}

// ---------------- GEMM: Y = xbf @ Bb^T, 64x64 tile, 4 waves -----------------
__global__ __launch_bounds__(256) void gemm_kernel(
    const unsigned short* __restrict__ xbf,   // [2048][256]
    const unsigned short* __restrict__ Bb,    // [896][256]
    float* __restrict__ Y)                    // [2048][896]
{
    __shared__ unsigned short As[64][LDSK];
    __shared__ unsigned short Bs[64][LDSK];

    const int tid  = threadIdx.x;
    const int m_base = blockIdx.x * 64;       // 0..31
    const int n_base = blockIdx.y * 64;       // 0..13
    const int lane = tid & 63, w = tid >> 6;
    const int lrow = lane & 15, quad = lane >> 4;

    floatx4 acc[4] = {floatx4{0,0,0,0}, floatx4{0,0,0,0},
                      floatx4{0,0,0,0}, floatx4{0,0,0,0}};

    for (int kh = 0; kh < 2; ++kh) {
        const int k0 = kh * 128;
        __syncthreads();
        #pragma unroll
        for (int it = 0; it < 4; ++it) {
            int idx = tid + it * 256;         // 1024 chunks of 16B
            int r = idx >> 4, cc = (idx & 15) * 8;
            uint4 av = *(const uint4*)(xbf + (size_t)(m_base + r) * CIN + k0 + cc);
            *(uint4*)&As[r][cc] = av;
            uint4 bv = *(const uint4*)(Bb  + (size_t)(n_base + r) * CIN + k0 + cc);
            *(uint4*)&Bs[r][cc] = bv;
        }
        __syncthreads();
        #pragma unroll
        for (int ks = 0; ks < 4; ++ks) {
            const int kc = ks * 32 + quad * 8;
            short8 af = *(const short8*)&As[w * 16 + lrow][kc];
            #pragma unroll
            for (int f = 0; f < 4; ++f) {
                short8 bfr = *(const short8*)&Bs[f * 16 + lrow][kc];
                acc[f] = __builtin_amdgcn_mfma_f32_16x16x32_bf16(af, bfr, acc[f], 0, 0, 0);
            }
        }
    }

    #pragma unroll
    for (int f = 0; f < 4; ++f)
        #pragma unroll
        for (int r = 0; r < 4; ++r)
            Y[(size_t)(m_base + w * 16 + quad * 4 + r) * NBIG + n_base + f * 16 + lrow]
                = acc[f][r];
}

// ---------------- epilogue (fp32): t then y --------------------------------
__global__ __launch_bounds__(256) void epilogue_kernel(
    const float* __restrict__ Y,          // [2048][896]
    const float* __restrict__ h,          // [2048][8]
    const float* __restrict__ fcwe_w,     // [256][64]
    const float* __restrict__ fcwe_b,     // [256]
    const float* __restrict__ fcbp_w,     // [256][8]
    const float* __restrict__ bias_const, // [256]
    float* __restrict__ out)              // [2048][256]
{
    __shared__ float tl[4][64];
    __shared__ float hl[4][NP];
    __shared__ float sxl[4];

    const int tid = threadIdx.x;
    const int b0  = blockIdx.x * 4;

    if (tid < 4 * NP) hl[tid >> 3][tid & 7] = h[(size_t)b0 * NP + tid];
    if (tid < 4)      sxl[tid] = Y[(size_t)(b0 + tid) * NBIG + 832];

    {   // t[s][m]
        int s = tid >> 6, m = tid & 63;
        const float* yr = Y + (size_t)(b0 + s) * NBIG;
        const float* hb = h + (size_t)(b0 + s) * NP;
        float4 u0 = *(const float4*)(yr + m * 8);
        float4 u1 = *(const float4*)(yr + m * 8 + 4);
        float t = yr[512 + m]
                + u0.x * hb[0] + u0.y * hb[1] + u0.z * hb[2] + u0.w * hb[3]
                + u1.x * hb[4] + u1.y * hb[5] + u1.z * hb[6] + u1.w * hb[7];
        tl[s][m] = t;
    }
    __syncthreads();

    const int o = tid;
    const float bc  = bias_const[o];
    const float web = fcwe_b[o];
    float y[4];
    #pragma unroll
    for (int s = 0; s < 4; ++s)
        y[s] = Y[(size_t)(b0 + s) * NBIG + 576 + o] + bc + web * sxl[s];

    const float* wer = fcwe_w + (size_t)o * MID;
    for (int mm = 0; mm < MID; mm += 4) {
        float4 w4 = *(const float4*)(wer + mm);
        #pragma unroll
        for (int s = 0; s < 4; ++s)
            y[s] += w4.x * tl[s][mm]     + w4.y * tl[s][mm + 1]
                  + w4.z * tl[s][mm + 2] + w4.w * tl[s][mm + 3];
    }
    const float* bpr = fcbp_w + (size_t)o * NP;
    float4 bp0 = *(const float4*)(bpr);
    float4 bp1 = *(const float4*)(bpr + 4);
    #pragma unroll
    for (int s = 0; s < 4; ++s)
        y[s] += bp0.x * hl[s][0] + bp0.y * hl[s][1] + bp0.z * hl[s][2] + bp0.w * hl[s][3]
              + bp1.x * hl[s][4] + bp1.y * hl[s][5] + bp1.z * hl[s][6] + bp1.w * hl[s][7];

    #pragma unroll
    for (int s = 0; s < 4; ++s)
        out[(size_t)(b0 + s) * COUT + o] = y[s];
}

extern "C" void kernel_launch(void* const* d_in, const int* in_sizes, int n_in,
                              void* d_out, int out_size, void* d_ws, size_t ws_size,
                              hipStream_t stream) {
    const float* x        = (const float*)d_in[0];
    const float* h        = (const float*)d_in[1];
    const float* index    = (const float*)d_in[2];
    const float* target_w = (const float*)d_in[3];
    const float* target_b = (const float*)d_in[4];
    const float* fcwp_w   = (const float*)d_in[5];
    const float* fcwp_b   = (const float*)d_in[6];
    const float* fcwi_w   = (const float*)d_in[7];
    const float* fcwi_b   = (const float*)d_in[8];
    const float* fcwe_w   = (const float*)d_in[9];
    const float* fcwe_b   = (const float*)d_in[10];
    const float* fcbp_w   = (const float*)d_in[11];
    const float* fcbp_b   = (const float*)d_in[12];
    const float* fcbi_w   = (const float*)d_in[13];
    const float* fcbi_b   = (const float*)d_in[14];
    float* out = (float*)d_out;

    // workspace layout
    char* ws = (char*)d_ws;
    float*          Y          = (float*)ws;                       // 2048*896*4 = 7340032
    unsigned short* xbf        = (unsigned short*)(ws + 7340032);  // 2048*256*2 = 1048576
    unsigned short* Bb         = (unsigned short*)(ws + 8388608);  // 896*256*2  = 458752
    float*          bias_const = (float*)(ws + 8847360);           // 256*4

    setup_kernel<<<1409, 256, 0, stream>>>(
        x, index, target_w, target_b, fcwp_w, fcwp_b, fcwi_w, fcwi_b,
        fcbp_b, fcbi_w, fcbi_b, xbf, Bb, bias_const);

    gemm_kernel<<<dim3(B_TOT / 64, NBIG / 64), 256, 0, stream>>>(xbf, Bb, Y);

    epilogue_kernel<<<B_TOT / 4, 256, 0, stream>>>(
        Y, h, fcwe_w, fcwe_b, fcbp_w, bias_const, out);
}